// Round 3
// baseline (229.144 us; speedup 1.0000x reference)
//
#include <hip/hip_runtime.h>

// ASTRF: trfs[b,o,w,s] = sum_i x[b,i,s]*weight[o,i,w]; out[b,o,src[b,s]+w] += trfs;
// out += bias[o]; trimmed to T. All tensors are float32 (per reference dtypes).
// GATHER formulation over per-block t-tiles: events found by binary search in
// the sorted sourceIdx, staged in LDS; each wave register-caches
// weight[o, :, lane] (lane == tap index d) so the hot loop is pure fp32 FMA
// with broadcast-LDS x operands into an LDS fp32 accumulator tile.

#define BB   4
#define II   16
#define SS   4096
#define OO   64
#define WW   64
#define TLEN 32768
#define TT   256      // t-tile per block
#define MAXEV 80      // event-chunk size (structural max per tile is ~47)

__global__ __launch_bounds__(256, 2) void astrf_gather(
    const float* __restrict__ x,      // (B, I, S)
    const float* __restrict__ w,      // (O, I, W)
    const float* __restrict__ bias,   // (O,)
    const int*   __restrict__ srcIdx, // (B, S) sorted per batch
    float*       __restrict__ out)    // (B, O, T)
{
    __shared__ __align__(16) float acc[OO * TT];   // 64 KB fp32 accumulator [o][t]
    __shared__ __align__(16) float xs[MAXEV * II]; // staged event x vectors [ev][i]
    __shared__ int   ssrc[MAXEV];
    __shared__ float sbias[OO];

    const int tid = threadIdx.x;
    const int b   = blockIdx.y;
    const int t0  = blockIdx.x * TT;

    // ---- zero the accumulator tile (float4 stores) ----
    float4* a4 = (float4*)acc;
    #pragma unroll
    for (int k = 0; k < (OO * TT / 4) / 256; ++k)
        a4[tid + k * 256] = make_float4(0.f, 0.f, 0.f, 0.f);
    if (tid < OO) sbias[tid] = bias[tid];

    // ---- event range for this tile: src in [t0-(W-1), t0+TT-1] ----
    const int* sp = srcIdx + b * SS;
    const int tmin = t0 - (WW - 1);
    int lo = 0, hi = SS;
    while (lo < hi) { int m = (lo + hi) >> 1; if (sp[m] < tmin) lo = m + 1; else hi = m; }
    const int e_lo = lo;
    int lo2 = e_lo, hi2 = SS;
    const int tmax = t0 + TT;
    while (lo2 < hi2) { int m = (lo2 + hi2) >> 1; if (sp[m] < tmax) lo2 = m + 1; else hi2 = m; }
    const int nev = lo2 - e_lo;

    const int wave = tid >> 6;
    const int lane = tid & 63;   // lane == tap index d in [0,64)

    for (int edone = 0; edone < nev; edone += MAXEV) {
        const int cn = min(nev - edone, MAXEV);
        __syncthreads();  // covers acc-zero on first iter, xs reuse on later iters

        // ---- stage this chunk's events: x[b,:,e] and src[e] ----
        // x is indexed by the EVENT index (e_lo+edone+ev), not the source time.
        for (int k = tid; k < cn * II; k += 256) {
            const int ev = k >> 4, i = k & 15;
            xs[k] = x[(b * II + i) * SS + (e_lo + edone + ev)];
        }
        for (int k = tid; k < cn; k += 256) ssrc[k] = sp[e_lo + edone + k];
        __syncthreads();

        // ---- each wave owns 16 o-channels, processed in register-chunks of 4 ----
        #pragma unroll
        for (int oc = 0; oc < 4; ++oc) {
            const int o0 = wave * 16 + oc * 4;
            float wr[4][II];   // weight[o0+j][i][lane] resident in VGPRs
            #pragma unroll
            for (int j = 0; j < 4; ++j)
                #pragma unroll
                for (int i = 0; i < II; ++i)
                    wr[j][i] = w[((o0 + j) * II + i) * WW + lane];

            for (int e = 0; e < cn; ++e) {
                const int off = ssrc[e] - t0;          // wave-uniform
                const int tl  = off + lane;            // target t within tile
                const bool pred = (unsigned)tl < (unsigned)TT;

                const float4* xp = (const float4*)&xs[e * II];  // broadcast b128 reads
                const float4 x0 = xp[0], x1 = xp[1], x2 = xp[2], x3 = xp[3];
                float xv[II] = { x0.x, x0.y, x0.z, x0.w,  x1.x, x1.y, x1.z, x1.w,
                                 x2.x, x2.y, x2.z, x2.w,  x3.x, x3.y, x3.z, x3.w };

                #pragma unroll
                for (int j = 0; j < 4; ++j) {
                    float y0 = 0.f, y1 = 0.f, y2 = 0.f, y3 = 0.f;  // 4 partials for ILP
                    #pragma unroll
                    for (int i = 0; i < II; i += 4) {
                        y0 = fmaf(xv[i + 0], wr[j][i + 0], y0);
                        y1 = fmaf(xv[i + 1], wr[j][i + 1], y1);
                        y2 = fmaf(xv[i + 2], wr[j][i + 2], y2);
                        y3 = fmaf(xv[i + 3], wr[j][i + 3], y3);
                    }
                    const float y = (y0 + y1) + (y2 + y3);
                    if (pred) acc[(o0 + j) * TT + tl] += y;  // per-o exclusive, in-wave sequential
                }
            }
        }
    }
    __syncthreads();

    // ---- epilogue: add bias, coalesced float4 stores ----
    for (int p = tid; p < OO * TT / 4; p += 256) {
        const int o  = p >> 6;          // p / (TT/4)
        const int t4 = (p & 63) << 2;   // 4-float group within tile
        const float bv = sbias[o];
        float4 v = *(const float4*)&acc[o * TT + t4];
        v.x += bv; v.y += bv; v.z += bv; v.w += bv;
        *(float4*)(out + ((size_t)(b * OO + o) * TLEN + t0 + t4)) = v;
    }
}

extern "C" void kernel_launch(void* const* d_in, const int* in_sizes, int n_in,
                              void* d_out, int out_size, void* d_ws, size_t ws_size,
                              hipStream_t stream) {
    const float* x    = (const float*)d_in[0];
    const float* wgt  = (const float*)d_in[1];
    const float* bias = (const float*)d_in[2];
    const int*   src  = (const int*)d_in[3];
    float* out = (float*)d_out;

    dim3 grid(TLEN / TT, BB);
    astrf_gather<<<grid, 256, 0, stream>>>(x, wgt, bias, src, out);
}

// Round 4
// 119.685 us; speedup vs baseline: 1.9146x; 1.9146x over previous
//
#include <hip/hip_runtime.h>

// ASTRF: trfs[b,o,w,s] = sum_i x[b,i,s]*weight[o,i,w]; out[b,o,src[b,s]+w] += trfs;
// out += bias[o]; trim to T. fp32 I/O. GATHER over (t-tile, o-group) blocks:
// events via binary search on sorted sourceIdx; weights register-resident per
// wave (4 o's x 16 i x lane==tap); fp32 LDS accumulator with 64-wide halo on
// both sides so the scatter-accumulate needs NO predication. o-split (16/block)
// keeps LDS at ~29KB -> 4 blocks/CU (16 waves/CU) vs round-3's 2 (8 waves/CU).

#define BB    4
#define II    16
#define SS    4096
#define OO    64
#define WW    64
#define TLEN  32768
#define TT    256            // t-tile per block
#define OB    16             // o-channels per block (4 waves x 4)
#define HALO  64
#define RW    (TT + 2*HALO)  // 384: accumulator row width (halo both sides)
#define MAXEV 64             // structural max events per tile is 47

__global__ __launch_bounds__(256, 4) void astrf_gather(
    const float* __restrict__ x,      // (B, I, S)
    const float* __restrict__ w,      // (O, I, W)
    const float* __restrict__ bias,   // (O,)
    const int*   __restrict__ srcIdx, // (B, S) sorted per batch
    float*       __restrict__ out)    // (B, O, T)
{
    __shared__ __align__(16) float acc[OB * RW];   // 24 KB fp32 accumulator [o][t+halo]
    __shared__ __align__(16) float xs[MAXEV * II]; // staged event x vectors [ev][i]
    __shared__ int   ssrc[MAXEV];
    __shared__ float sbias[OB];

    const int tid    = threadIdx.x;
    const int t0     = blockIdx.x * TT;
    const int o_base = blockIdx.y * OB;
    const int b      = blockIdx.z;

    // ---- zero the accumulator tile (incl. halo) ----
    float4* a4 = (float4*)acc;
    #pragma unroll
    for (int k = 0; k < (OB * RW / 4) / 256; ++k)
        a4[tid + k * 256] = make_float4(0.f, 0.f, 0.f, 0.f);
    if (tid < OB) sbias[tid] = bias[o_base + tid];

    // ---- event range for this tile: src in [t0-(W-1), t0+TT-1] ----
    const int* sp = srcIdx + b * SS;
    const int tmin = t0 - (WW - 1);
    int lo = 0, hi = SS;
    while (lo < hi) { int m = (lo + hi) >> 1; if (sp[m] < tmin) lo = m + 1; else hi = m; }
    const int e_lo = lo;
    int lo2 = e_lo, hi2 = SS;
    const int tmax = t0 + TT;
    while (lo2 < hi2) { int m = (lo2 + hi2) >> 1; if (sp[m] < tmax) lo2 = m + 1; else hi2 = m; }
    const int nev = lo2 - e_lo;

    const int wave = tid >> 6;
    const int lane = tid & 63;   // lane == tap index d in [0,64)

    // ---- weights register-resident for this wave's 4 o's (loaded ONCE) ----
    const int o0 = o_base + wave * 4;
    float wr[4][II];
    #pragma unroll
    for (int j = 0; j < 4; ++j)
        #pragma unroll
        for (int i = 0; i < II; ++i)
            wr[j][i] = w[((o0 + j) * II + i) * WW + lane];
    const int arow = wave * 4 * RW;   // this wave's first acc row

    for (int edone = 0; edone < nev; edone += MAXEV) {  // runs once (nev <= 47)
        const int cn = min(nev - edone, MAXEV);
        __syncthreads();  // acc-zero visible / xs reuse safe

        // ---- stage this chunk's events: x[b,:,e] and src[e] ----
        for (int k = tid; k < cn * II; k += 256) {
            const int ev = k >> 4, i = k & 15;
            xs[k] = x[(b * II + i) * SS + (e_lo + edone + ev)];
        }
        for (int k = tid; k < cn; k += 256) ssrc[k] = sp[e_lo + edone + k];
        __syncthreads();

        for (int e = 0; e < cn; ++e) {
            const int pos = ssrc[e] - t0 + HALO + lane;   // in [1, 382] always

            const float4* xp = (const float4*)&xs[e * II];  // broadcast b128 reads
            const float4 x0 = xp[0], x1 = xp[1], x2 = xp[2], x3 = xp[3];
            const float xv[II] = { x0.x, x0.y, x0.z, x0.w,  x1.x, x1.y, x1.z, x1.w,
                                   x2.x, x2.y, x2.z, x2.w,  x3.x, x3.y, x3.z, x3.w };

            #pragma unroll
            for (int j = 0; j < 4; ++j) {
                float y0 = 0.f, y1 = 0.f, y2 = 0.f, y3 = 0.f;  // 4 partials for ILP
                #pragma unroll
                for (int i = 0; i < II; i += 4) {
                    y0 = fmaf(xv[i + 0], wr[j][i + 0], y0);
                    y1 = fmaf(xv[i + 1], wr[j][i + 1], y1);
                    y2 = fmaf(xv[i + 2], wr[j][i + 2], y2);
                    y3 = fmaf(xv[i + 3], wr[j][i + 3], y3);
                }
                // unconditional RMW into halo'd row; per-o row exclusive to this
                // wave, events sequential within the wave -> race-free
                acc[arow + j * RW + pos] += (y0 + y1) + (y2 + y3);
            }
        }
    }
    __syncthreads();

    // ---- epilogue: drop halo, add bias, coalesced float4 stores ----
    #pragma unroll
    for (int k = 0; k < (OB * TT / 4) / 256; ++k) {
        const int p  = tid + k * 256;
        const int o  = p >> 6;          // p / (TT/4)
        const int t4 = (p & 63) << 2;
        const float bv = sbias[o];
        float4 v = *(const float4*)&acc[o * RW + HALO + t4];
        v.x += bv; v.y += bv; v.z += bv; v.w += bv;
        *(float4*)(out + ((size_t)(b * OO + o_base + o) * TLEN + t0 + t4)) = v;
    }
}

extern "C" void kernel_launch(void* const* d_in, const int* in_sizes, int n_in,
                              void* d_out, int out_size, void* d_ws, size_t ws_size,
                              hipStream_t stream) {
    const float* x    = (const float*)d_in[0];
    const float* wgt  = (const float*)d_in[1];
    const float* bias = (const float*)d_in[2];
    const int*   src  = (const int*)d_in[3];
    float* out = (float*)d_out;

    dim3 grid(TLEN / TT, OO / OB, BB);   // (128, 4, 4) = 2048 blocks
    astrf_gather<<<grid, 256, 0, stream>>>(x, wgt, bias, src, out);
}

// Round 5
// 115.050 us; speedup vs baseline: 1.9917x; 1.0403x over previous
//
#include <hip/hip_runtime.h>

// ASTRF fp32: out[b,o,src[b,s]+w] += sum_i x[b,i,s]*weight[o,i,w]; out += bias.
// Gather over (t-tile=256, o-group=16, b) blocks. Round-5 structure:
//  - x pre-transposed to xt[b][e][i] (d_ws) -> per-event x is ONE uniform 64B load
//  - weights register-resident as float2 i-pairs; inner loop = 32 v_pk_fma_f32
//  - acc LDS layout [pos][o] (row padded to 20 words) -> per-event RMW is a
//    single ds_read_b128 + ds_write_b128, conflict-free (20-stride covers all
//    32 banks in the minimal 8 phases)
//  - event range from analytic seed + bidirectional fixup (sp[e] ~ 7e+jitter)

#define BB    4
#define II    16
#define SS    4096
#define OO    64
#define WW    64
#define TLEN  32768
#define TT    256            // t-tile per block
#define OB    16             // o-channels per block (4 waves x 4)
#define HALO  64
#define RW    (TT + 2*HALO)  // 384 accumulator rows
#define ROWW  20             // padded row width (16 o's + 4 pad), b128-aligned

typedef float v2f __attribute__((ext_vector_type(2)));

__global__ void xpose(const float* __restrict__ x, float* __restrict__ xt) {
    // grid (S/64, B), 256 threads: x (B,I,S) -> xt (B,S,I)
    __shared__ float tile[II][64 + 1];
    const int b = blockIdx.y, e0 = blockIdx.x * 64, tid = threadIdx.x;
    const int i = tid >> 6, el = tid & 63;
    #pragma unroll
    for (int k = 0; k < 4; ++k)
        tile[i + 4 * k][el] = x[((size_t)(b * II + i + 4 * k)) * SS + e0 + el];
    __syncthreads();
    const int e = tid >> 2, iq = tid & 3;
    float4 v = { tile[4 * iq + 0][e], tile[4 * iq + 1][e],
                 tile[4 * iq + 2][e], tile[4 * iq + 3][e] };
    *(float4*)(xt + ((size_t)(b * SS + e0 + e)) * II + 4 * iq) = v;
}

__global__ __launch_bounds__(256, 4) void astrf_gather(
    const float* __restrict__ xt,     // (B, S, I)  transposed x
    const float* __restrict__ w,      // (O, I, W)
    const float* __restrict__ bias,   // (O,)
    const int*   __restrict__ srcIdx, // (B, S) sorted per batch
    float*       __restrict__ out)    // (B, O, T)
{
    __shared__ __align__(16) float acc[RW * ROWW];   // 30.7 KB [pos][o(+pad)]

    const int tid    = threadIdx.x;
    const int t0     = blockIdx.x * TT;
    const int o_base = blockIdx.y * OB;
    const int b      = blockIdx.z;
    const int wave   = tid >> 6;
    const int lane   = tid & 63;     // lane == tap index d

    // ---- zero accumulator ----
    float4* a4 = (float4*)acc;
    #pragma unroll
    for (int k = 0; k < 8; ++k) {
        const int p = tid + k * 256;
        if (p < RW * ROWW / 4) a4[p] = make_float4(0.f, 0.f, 0.f, 0.f);
    }

    // ---- event range: src in [t0-(W-1), t0+TT-1]; sp[e] = 7e + jitter(0..6) ----
    const int* sp = srcIdx + b * SS;
    const int tmin = t0 - (WW - 1);
    const int tmax = t0 + TT;
    int e_lo = tmin > 6 ? (tmin - 6) / 7 : 0;  if (e_lo > SS) e_lo = SS;
    while (e_lo > 0 && sp[e_lo - 1] >= tmin) --e_lo;
    while (e_lo < SS && sp[e_lo] < tmin) ++e_lo;
    int e_hi = tmax > 0 ? tmax / 7 : 0;  if (e_hi > SS) e_hi = SS;
    while (e_hi > 0 && sp[e_hi - 1] >= tmax) --e_hi;
    while (e_hi < SS && sp[e_hi] < tmax) ++e_hi;

    // ---- weights register-resident: this wave's 4 o's, as i-pairs ----
    const int o0 = o_base + wave * 4;
    v2f wr2[4][8];
    #pragma unroll
    for (int j = 0; j < 4; ++j)
        #pragma unroll
        for (int i2 = 0; i2 < 8; ++i2) {
            wr2[j][i2].x = w[((o0 + j) * II + 2 * i2 + 0) * WW + lane];
            wr2[j][i2].y = w[((o0 + j) * II + 2 * i2 + 1) * WW + lane];
        }

    __syncthreads();   // acc zeros visible before RMW

    // ---- event loop: uniform x row load, 32 pk_fma, one b128 RMW ----
    const float* xrow = xt + (size_t)b * SS * II;
    for (int e = e_lo; e < e_hi; ++e) {
        const int se = sp[e];                       // uniform scalar
        const float4* xq = (const float4*)(xrow + (size_t)e * II);
        const float4 q0 = xq[0], q1 = xq[1], q2 = xq[2], q3 = xq[3];
        const v2f xh[8] = { {q0.x,q0.y},{q0.z,q0.w},{q1.x,q1.y},{q1.z,q1.w},
                            {q2.x,q2.y},{q2.z,q2.w},{q3.x,q3.y},{q3.z,q3.w} };

        const int word = (se - t0 + HALO + lane) * ROWW + (wave << 2);
        const float4 old = *(const float4*)&acc[word];

        v2f y0 = {0.f,0.f}, y1 = {0.f,0.f}, y2 = {0.f,0.f}, y3 = {0.f,0.f};
        #pragma unroll
        for (int i2 = 0; i2 < 8; ++i2) {
            y0 = __builtin_elementwise_fma(xh[i2], wr2[0][i2], y0);
            y1 = __builtin_elementwise_fma(xh[i2], wr2[1][i2], y1);
            y2 = __builtin_elementwise_fma(xh[i2], wr2[2][i2], y2);
            y3 = __builtin_elementwise_fma(xh[i2], wr2[3][i2], y3);
        }
        float4 nv;
        nv.x = old.x + (y0.x + y0.y);
        nv.y = old.y + (y1.x + y1.y);
        nv.z = old.z + (y2.x + y2.y);
        nv.w = old.w + (y3.x + y3.y);
        *(float4*)&acc[word] = nv;   // per-wave-exclusive 16B chunk; in-order DS
    }
    __syncthreads();

    // ---- epilogue: o = 4*wave + j, t = lane + 64c; coalesced b32 stores ----
    #pragma unroll
    for (int j = 0; j < 4; ++j) {
        const int o  = (wave << 2) + j;
        const float bv = bias[o_base + o];
        float* orow = out + ((size_t)(b * OO + o_base + o)) * TLEN + t0;
        #pragma unroll
        for (int c = 0; c < 4; ++c) {
            const int t = lane + 64 * c;
            orow[t] = acc[(HALO + t) * ROWW + o] + bv;
        }
    }
}

extern "C" void kernel_launch(void* const* d_in, const int* in_sizes, int n_in,
                              void* d_out, int out_size, void* d_ws, size_t ws_size,
                              hipStream_t stream) {
    const float* x    = (const float*)d_in[0];
    const float* wgt  = (const float*)d_in[1];
    const float* bias = (const float*)d_in[2];
    const int*   src  = (const int*)d_in[3];
    float* out = (float*)d_out;
    float* xt  = (float*)d_ws;            // B*S*I floats = 1 MB

    xpose<<<dim3(SS / 64, BB), 256, 0, stream>>>(x, xt);
    dim3 grid(TLEN / TT, OO / OB, BB);    // (128, 4, 4)
    astrf_gather<<<grid, 256, 0, stream>>>(xt, wgt, bias, src, out);
}

// Round 6
// 92.424 us; speedup vs baseline: 2.4793x; 1.2448x over previous
//
#include <hip/hip_runtime.h>

// ASTRF via dense-conv identity: y[b,i,tau]=x[b,i,e] at tau=src[b,e] (unique
// per batch), then out[b,o,t] = bias[o] + sum_{i,d} w[o,i,d] * y[b,i,t-d].
// Per (b, 256-t-tile) block this is an MFMA GEMM: M=64 (o), N=256 (t),
// K=I*W=1024 with k=(d,i) ordering so A- and B-fragments are single
// ds_read_b128s. A = w2[o][k] bf16 (pre-transformed), B = im2col of the
// y tile (shift-by-d reads of the LDS [pos][i] tile).

#define BB 4
#define II 16
#define SS 4096
#define OO 64
#define WW 64
#define TLEN 32768
#define KK 1024        // II*WW
#define KC 128         // K-chunk staged per dbuf phase
#define TT 256         // t per block
#define YROWPAD 24     // yt LDS row stride in bf16 elems (48 B, 16B-aligned, bank-spread)
#define AROWPAD 136    // aL row stride in bf16 elems (272 B)
#define YR 32848       // y global rows: 64 left pad + 32768 + 16 slack

typedef short bf16x8 __attribute__((ext_vector_type(8)));
typedef float f32x4  __attribute__((ext_vector_type(4)));

static __device__ __forceinline__ ushort f2bf(float f) {
    union { float f; uint u; } v; v.f = f;
    const uint u = v.u;
    return (ushort)((u + 0x7FFFu + ((u >> 16) & 1u)) >> 16);   // RNE
}

// ---- w (O,I,W) fp32 -> w2 (O, K) bf16 with k = d*16 + i (read-coalesced) ----
__global__ void prep_w(const float* __restrict__ w, ushort* __restrict__ w2) {
    const int idx = blockIdx.x * 256 + threadIdx.x;   // 65536 = O*I*W
    const int o = idx >> 10, i = (idx >> 6) & 15, d = idx & 63;
    w2[o * KK + d * II + i] = f2bf(w[idx]);
}

// ---- scatter x onto timeline: y[b][64+src[b,e]][i] = bf16(x[b,i,e]) ----
__global__ void scat_y(const float* __restrict__ x, const int* __restrict__ srcIdx,
                       ushort* __restrict__ y) {
    __shared__ float tile[II][64 + 1];
    const int b = blockIdx.y, e0 = blockIdx.x * 64, tid = threadIdx.x;
    const int i = tid >> 6, el = tid & 63;
    #pragma unroll
    for (int k = 0; k < 4; ++k)
        tile[i + 4 * k][el] = x[((size_t)(b * II + i + 4 * k)) * SS + e0 + el];
    __syncthreads();
    const int e = tid >> 2, iq = tid & 3;   // 4 threads per event, 4 i's each
    ushort4 v;
    v.x = f2bf(tile[4 * iq + 0][e]);
    v.y = f2bf(tile[4 * iq + 1][e]);
    v.z = f2bf(tile[4 * iq + 2][e]);
    v.w = f2bf(tile[4 * iq + 3][e]);
    const int row = 64 + srcIdx[b * SS + e0 + e];
    *(ushort4*)(y + ((size_t)b * YR + row) * II + iq * 4) = v;
}

__global__ __launch_bounds__(256, 2) void astrf_mfma(
    const ushort* __restrict__ w2,    // (O, K) bf16
    const ushort* __restrict__ y,     // (B, YR, II) bf16
    const float* __restrict__ bias,   // (O,)
    float* __restrict__ out)          // (B, O, T)
{
    __shared__ __align__(16) ushort yt[320 * YROWPAD];     // 15,360 B y tile [p][i]
    __shared__ __align__(16) ushort aL[2][OO * AROWPAD];   // 2 x 17,408 B A dbuf
    __shared__ float sbias[OO];

    const int tid  = threadIdx.x;
    const int t0   = blockIdx.x * TT;
    const int b    = blockIdx.y;
    const int wave = tid >> 6, lane = tid & 63;
    const int nl   = lane & 15, kg = lane >> 4;

    // ---- stage y tile: rows p=0..319  <-  y[b][t0+1+p][:]  (tau = t0-63+p) ----
    {
        const uint4* src = (const uint4*)(y + ((size_t)b * YR + (t0 + 1)) * II);
        for (int c = tid; c < 640; c += 256) {           // 640 x 16B halves
            const int p = c >> 1, h = c & 1;
            const uint4 v = src[p * 2 + h];
            *(uint4*)&yt[p * YROWPAD + h * 8] = v;
        }
    }
    if (tid < OO) sbias[tid] = bias[tid];

    // ---- prefetch + stage A chunk 0 ----
    uint4 pf[4];
    #pragma unroll
    for (int j = 0; j < 4; ++j) {
        const int u = tid + j * 256, o = u >> 4, q = u & 15;   // 1024 x 16B
        pf[j] = *(const uint4*)(w2 + (size_t)o * KK + q * 8);
    }
    #pragma unroll
    for (int j = 0; j < 4; ++j) {
        const int u = tid + j * 256, o = u >> 4, q = u & 15;
        *(uint4*)&aL[0][o * AROWPAD + q * 8] = pf[j];
    }
    __syncthreads();

    f32x4 acc[4][4];
    #pragma unroll
    for (int m = 0; m < 4; ++m)
        #pragma unroll
        for (int n = 0; n < 4; ++n)
            acc[m][n] = (f32x4){0.f, 0.f, 0.f, 0.f};

    for (int kc = 0; kc < 8; ++kc) {
        if (kc < 7) {   // prefetch next A chunk (global latency overlaps MFMA)
            #pragma unroll
            for (int j = 0; j < 4; ++j) {
                const int u = tid + j * 256, o = u >> 4, q = u & 15;
                pf[j] = *(const uint4*)(w2 + (size_t)o * KK + (kc + 1) * KC + q * 8);
            }
        }
        const ushort* aB = aL[kc & 1];
        #pragma unroll
        for (int ks = 0; ks < 4; ++ks) {
            bf16x8 afr[4];
            const int koff = ks * 32 + kg * 8;
            #pragma unroll
            for (int m = 0; m < 4; ++m)
                afr[m] = *(const bf16x8*)&aB[(m * 16 + nl) * AROWPAD + koff];
            const int d  = kc * 8 + ks * 2 + (kg >> 1);   // tap index of this k-group
            const int i0 = (kg & 1) * 8;                  // i half
            #pragma unroll
            for (int n = 0; n < 4; ++n) {
                const int p = (wave * 4 + n) * 16 + nl + 63 - d;   // in [0,318]
                const bf16x8 bfr = *(const bf16x8*)&yt[p * YROWPAD + i0];
                #pragma unroll
                for (int m = 0; m < 4; ++m)
                    acc[m][n] = __builtin_amdgcn_mfma_f32_16x16x32_bf16(
                        afr[m], bfr, acc[m][n], 0, 0, 0);
            }
        }
        if (kc < 7) {
            #pragma unroll
            for (int j = 0; j < 4; ++j) {
                const int u = tid + j * 256, o = u >> 4, q = u & 15;
                *(uint4*)&aL[(kc + 1) & 1][o * AROWPAD + q * 8] = pf[j];
            }
        }
        __syncthreads();   // one barrier per K-chunk (dbuf)
    }

    // ---- epilogue: D lane map col=lane&15, row=kg*4+r ----
    #pragma unroll
    for (int m = 0; m < 4; ++m)
        #pragma unroll
        for (int n = 0; n < 4; ++n) {
            const int t = t0 + (wave * 4 + n) * 16 + nl;
            #pragma unroll
            for (int r = 0; r < 4; ++r) {
                const int o = m * 16 + kg * 4 + r;
                out[((size_t)(b * OO + o)) * TLEN + t] = acc[m][n][r] + sbias[o];
            }
        }
}

extern "C" void kernel_launch(void* const* d_in, const int* in_sizes, int n_in,
                              void* d_out, int out_size, void* d_ws, size_t ws_size,
                              hipStream_t stream) {
    const float* x    = (const float*)d_in[0];
    const float* wgt  = (const float*)d_in[1];
    const float* bias = (const float*)d_in[2];
    const int*   src  = (const int*)d_in[3];
    float* out = (float*)d_out;

    ushort* w2 = (ushort*)d_ws;                              // 128 KB
    ushort* y  = (ushort*)((char*)d_ws + 131072);            // 4*YR*32 B ~ 4.2 MB

    prep_w<<<dim3(OO * KK / 256), 256, 0, stream>>>(wgt, w2);
    hipMemsetAsync(y, 0, (size_t)BB * YR * II * sizeof(ushort), stream);
    scat_y<<<dim3(SS / 64, BB), 256, 0, stream>>>(x, src, y);
    astrf_mfma<<<dim3(TLEN / TT, BB), 256, 0, stream>>>(w2, y, bias, out);
}